// Round 15
// baseline (75.386 us; speedup 1.0000x reference)
//
#include <hip/hip_runtime.h>
#include <hip/hip_bf16.h>

// DeconvCapsuleLayer fused kernel, round 15.
// = round 13 grid/occupancy (2560 blocks, (256,5)) with the routing rewritten
// ENTIRELY in the transposed (T) layout:
//   - only accT is computed (16 MFMAs/pair, was 32: the orig-layout acc and
//     its preact fma chains are deleted)
//   - ZERO LDS bridges (was 4 ds_write->lgkmcnt(0)->ds_read round-trips/pair):
//     IC-sum = 3-stage DPP reduce over lane bits 0-2; oa-norm = in-lane r-sum
//     + permlane16/32 joins over g; act lands per-lane exactly where the
//     logit-update dot needs it.
//   - round-14's load prefetch reverted (neutral at lower occupancy).
//
// T layout: lane = g*16 + pi, pi = p*8 + ic;  accT[oc][r] = votes[p][ic][oc]
// [oa = g*4+r].
//
// Conv-transpose (stride 2, K=4, SAME -> pad 1): with o = 2*y+py:
//   ky = 2*ty + (py^1), iy = y + py - ty, valid iff 0<=iy<56 (same for x).

typedef __attribute__((ext_vector_type(8))) short bf16x8;
typedef __attribute__((ext_vector_type(4))) float f32x4;

// 8 floats (two f32x4) -> bf16x8 via 4x native packed converts (RNE).
static __device__ __forceinline__ bf16x8 cvt8(f32x4 a, f32x4 b) {
    union { unsigned u[4]; bf16x8 v; } r;
    asm("v_cvt_pk_bf16_f32 %0, %1, %2" : "=v"(r.u[0]) : "v"(a[0]), "v"(a[1]));
    asm("v_cvt_pk_bf16_f32 %0, %1, %2" : "=v"(r.u[1]) : "v"(a[2]), "v"(a[3]));
    asm("v_cvt_pk_bf16_f32 %0, %1, %2" : "=v"(r.u[2]) : "v"(b[0]), "v"(b[1]));
    asm("v_cvt_pk_bf16_f32 %0, %1, %2" : "=v"(r.u[3]) : "v"(b[2]), "v"(b[3]));
    return r.v;
}

// Build a raw-buffer SRD (stride=0 -> num_records in BYTES, raw dword mode).
static __device__ __forceinline__ __amdgpu_buffer_rsrc_t
make_srd(const void* base, int nrec) {
    uintptr_t p = (uintptr_t)base;
    unsigned lo = (unsigned)__builtin_amdgcn_readfirstlane((int)p);
    unsigned hi = (unsigned)__builtin_amdgcn_readfirstlane((int)(p >> 32));
    nrec = __builtin_amdgcn_readfirstlane(nrec);
    void* bp = (void*)(((uintptr_t)hi << 32) | lo);
    return __builtin_amdgcn_make_buffer_rsrc(bp, (short)0, nrec, 0x00020000);
}

// Four interleaved 8-lane all-reduce sums over lane bits 0-2 (the ic axis):
// xor1 (quad_perm), xor2 (quad_perm), xor4-equivalent (row_half_mirror after
// quads uniform). Broadcasts the ic-sum to all 8 lanes of each half-row.
static __device__ __forceinline__ void dpp_sum8_x4(float& a, float& b,
                                                   float& c, float& d) {
    asm("s_nop 1\n\t"
        "v_add_f32_dpp %0, %0, %0 quad_perm:[1,0,3,2] row_mask:0xf bank_mask:0xf\n\t"
        "v_add_f32_dpp %1, %1, %1 quad_perm:[1,0,3,2] row_mask:0xf bank_mask:0xf\n\t"
        "v_add_f32_dpp %2, %2, %2 quad_perm:[1,0,3,2] row_mask:0xf bank_mask:0xf\n\t"
        "v_add_f32_dpp %3, %3, %3 quad_perm:[1,0,3,2] row_mask:0xf bank_mask:0xf\n\t"
        "v_add_f32_dpp %0, %0, %0 quad_perm:[2,3,0,1] row_mask:0xf bank_mask:0xf\n\t"
        "v_add_f32_dpp %1, %1, %1 quad_perm:[2,3,0,1] row_mask:0xf bank_mask:0xf\n\t"
        "v_add_f32_dpp %2, %2, %2 quad_perm:[2,3,0,1] row_mask:0xf bank_mask:0xf\n\t"
        "v_add_f32_dpp %3, %3, %3 quad_perm:[2,3,0,1] row_mask:0xf bank_mask:0xf\n\t"
        "v_add_f32_dpp %0, %0, %0 row_half_mirror row_mask:0xf bank_mask:0xf\n\t"
        "v_add_f32_dpp %1, %1, %1 row_half_mirror row_mask:0xf bank_mask:0xf\n\t"
        "v_add_f32_dpp %2, %2, %2 row_half_mirror row_mask:0xf bank_mask:0xf\n\t"
        "v_add_f32_dpp %3, %3, %3 row_half_mirror row_mask:0xf bank_mask:0xf"
        : "+v"(a), "+v"(b), "+v"(c), "+v"(d));
}

// xor16 pair-sum (v_permlane16_swap + add; both regs equal -> direction moot).
static __device__ __forceinline__ void join16_x4(float& p0, float& p1,
                                                 float& p2, float& p3) {
    float q0 = p0, q1 = p1, q2 = p2, q3 = p3;
    asm("s_nop 1\n\t"
        "v_permlane16_swap_b32 %0, %4\n\t"
        "v_permlane16_swap_b32 %1, %5\n\t"
        "v_permlane16_swap_b32 %2, %6\n\t"
        "v_permlane16_swap_b32 %3, %7"
        : "+v"(p0), "+v"(p1), "+v"(p2), "+v"(p3),
          "+v"(q0), "+v"(q1), "+v"(q2), "+v"(q3));
    p0 += q0; p1 += q1; p2 += q2; p3 += q3;
}

// xor32 pair-sum.
static __device__ __forceinline__ void join32_x4(float& p0, float& p1,
                                                 float& p2, float& p3) {
    float q0 = p0, q1 = p1, q2 = p2, q3 = p3;
    asm("s_nop 1\n\t"
        "v_permlane32_swap_b32 %0, %4\n\t"
        "v_permlane32_swap_b32 %1, %5\n\t"
        "v_permlane32_swap_b32 %2, %6\n\t"
        "v_permlane32_swap_b32 %3, %7"
        : "+v"(p0), "+v"(p1), "+v"(p2), "+v"(p3),
          "+v"(q0), "+v"(q1), "+v"(q2), "+v"(q3));
    p0 += q0; p1 += q1; p2 += q2; p3 += q3;
}

__global__ __launch_bounds__(256, 5)
void caps_deconv_route(const float* __restrict__ in, const float* __restrict__ Wt,
                       const float* __restrict__ bia, float* __restrict__ out) {
    const int tid  = threadIdx.x;
    const int lane = tid & 63;
    const int wid  = tid >> 6;

    // XCD-aware mapping: b = h&7 -> each XCD owns one batch. Grid 2560 =
    // 8 b x 4 cls x 80 blocks; per (b,cls): 320 waves = 288x5 + 32x4 pairs.
    const int h    = blockIdx.x;       // 0..2559
    const int b    = h & 7;
    const int r    = h >> 3;           // 0..319
    const int s80  = r >> 2;           // 0..79
    const int cls  = r & 3;
    const int py = cls >> 1, px = cls & 1;

    const int wv = s80*4 + wid;        // 0..319 within (b,cls)
    int start, np;
    if (wv < 288) { start = wv*5;       np = 5; }
    else          { start = 4*wv + 288; np = 4; }

    // ---- stage weights (this parity class) into LDS as bf16 B-fragments ----
    // uint4[(s*4 + ko)*64 + ch], ch = oc*16+oa; each uint4 = 8 bf16 (ci octet)
    __shared__ uint4 wlds[1024];        // 16 KB
    for (int t = tid; t < 1024; t += 256) {
        const int s  = t >> 8;
        const int ko = (t >> 6) & 3;
        const int ch = t & 63;
        const int ky = 2*(s >> 1) + (py ^ 1);
        const int kx = 2*(s & 1)  + (px ^ 1);
        const float* wp = Wt + (((ky*4 + kx)*64 + ch)*32 + ko*8);
        const float4 w0 = *(const float4*)(wp);
        const float4 w1 = *(const float4*)(wp + 4);
        uint4 u;
        asm("v_cvt_pk_bf16_f32 %0, %1, %2" : "=v"(u.x) : "v"(w0.x), "v"(w0.y));
        asm("v_cvt_pk_bf16_f32 %0, %1, %2" : "=v"(u.y) : "v"(w0.z), "v"(w0.w));
        asm("v_cvt_pk_bf16_f32 %0, %1, %2" : "=v"(u.z) : "v"(w1.x), "v"(w1.y));
        asm("v_cvt_pk_bf16_f32 %0, %1, %2" : "=v"(u.w) : "v"(w1.z), "v"(w1.w));
        wlds[t] = u;
    }
    __syncthreads();

    const int col  = lane & 15;   // pi = p*8 + ic
    const int g    = lane >> 4;   // oa group (oa = g*4 + r)
    const int wbase = g*64 + col;
    const int p_   = col >> 3;    // position within the pair
    const int icl  = col & 7;     // input capsule

    // A-fragment row mapping (same register serves as MFMA B-operand):
    const int a_pos = (lane >> 3) & 1;
    const int a_ic  = lane & 7;

    // bias in T layout: biasT[oc][r] = bia[oc*16 + g*4 + r]
    float4 biasT[4];
    #pragma unroll
    for (int oc = 0; oc < 4; ++oc) biasT[oc] = *(const float4*)&bia[oc*16 + g*4];

    // per-lane byte offset within one input row image (56 cols * 256 f32 * 4B)
    const int laneoff = a_pos*1024 + a_ic*128 + g*32;

    int p0v = start * 2;
    int y  = p0v / 56;
    int x0 = p0v - y*56;   // pairs advance by 2; 56 even -> never crosses rows

    for (int i = 0; i < np; ++i) {
        // ---- per-row buffer descriptors (wave-uniform via readfirstlane) ----
        const int iy0 = y + py, iy1 = y + py - 1;
        const __amdgpu_buffer_rsrc_t srd0 = make_srd(
            (const char*)in + (size_t)(b*56 + (iy0 < 0 ? 0 : (iy0 > 55 ? 55 : iy0))) * 57344,
            ((unsigned)iy0 < 56u) ? 57344 : 0);
        const __amdgpu_buffer_rsrc_t srd1 = make_srd(
            (const char*)in + (size_t)(b*56 + (iy1 < 0 ? 0 : (iy1 > 55 ? 55 : iy1))) * 57344,
            ((unsigned)iy1 < 56u) ? 57344 : 0);
        // voffset: ix*1024 + laneoff; tx=1 -> -1024 (unsigned wrap -> OOB -> 0)
        const int voff0 = (x0 + px) * 1024 + laneoff;
        const int voff1 = voff0 - 1024;

        // ---- A-tap loads: HW bounds check zeroes all out-of-range taps ----
        f32x4 t0a = __builtin_bit_cast(f32x4, __builtin_amdgcn_raw_buffer_load_b128(srd0, voff0,      0, 0));
        f32x4 t0b = __builtin_bit_cast(f32x4, __builtin_amdgcn_raw_buffer_load_b128(srd0, voff0 + 16, 0, 0));
        f32x4 t1a = __builtin_bit_cast(f32x4, __builtin_amdgcn_raw_buffer_load_b128(srd0, voff1,      0, 0));
        f32x4 t1b = __builtin_bit_cast(f32x4, __builtin_amdgcn_raw_buffer_load_b128(srd0, voff1 + 16, 0, 0));
        f32x4 t2a = __builtin_bit_cast(f32x4, __builtin_amdgcn_raw_buffer_load_b128(srd1, voff0,      0, 0));
        f32x4 t2b = __builtin_bit_cast(f32x4, __builtin_amdgcn_raw_buffer_load_b128(srd1, voff0 + 16, 0, 0));
        f32x4 t3a = __builtin_bit_cast(f32x4, __builtin_amdgcn_raw_buffer_load_b128(srd1, voff1,      0, 0));
        f32x4 t3b = __builtin_bit_cast(f32x4, __builtin_amdgcn_raw_buffer_load_b128(srd1, voff1 + 16, 0, 0));

        bf16x8 af0 = cvt8(t0a, t0b);
        bf16x8 af1 = cvt8(t1a, t1b);
        bf16x8 af2 = cvt8(t2a, t2b);
        bf16x8 af3 = cvt8(t3a, t3b);

        // ---- votes, T layout only: accT[oc][r] = votes[pi][oc][oa=g*4+r] ----
        f32x4 accT[4];
        __builtin_amdgcn_s_setprio(1);
        #pragma unroll
        for (int nt = 0; nt < 4; ++nt) {
            bf16x8 wf = __builtin_bit_cast(bf16x8, wlds[wbase + nt*16]);
            accT[nt] = __builtin_amdgcn_mfma_f32_16x16x32_bf16(
                wf, af0, (f32x4){0.f,0.f,0.f,0.f}, 0, 0, 0);
        }
        #pragma unroll
        for (int nt = 0; nt < 4; ++nt) {
            bf16x8 wf = __builtin_bit_cast(bf16x8, wlds[wbase + 256 + nt*16]);
            accT[nt] = __builtin_amdgcn_mfma_f32_16x16x32_bf16(wf, af1, accT[nt], 0, 0, 0);
        }
        #pragma unroll
        for (int nt = 0; nt < 4; ++nt) {
            bf16x8 wf = __builtin_bit_cast(bf16x8, wlds[wbase + 512 + nt*16]);
            accT[nt] = __builtin_amdgcn_mfma_f32_16x16x32_bf16(wf, af2, accT[nt], 0, 0, 0);
        }
        #pragma unroll
        for (int nt = 0; nt < 4; ++nt) {
            bf16x8 wf = __builtin_bit_cast(bf16x8, wlds[wbase + 768 + nt*16]);
            accT[nt] = __builtin_amdgcn_mfma_f32_16x16x32_bf16(wf, af3, accT[nt], 0, 0, 0);
        }
        __builtin_amdgcn_s_setprio(0);

        float S[4][4], actT[4][4], sqv[4], logit[4];

        // ---- iter 1 (logits=0 -> route=0.25 exactly) ----
        #pragma unroll
        for (int oc = 0; oc < 4; ++oc)
            #pragma unroll
            for (int rr = 0; rr < 4; ++rr) S[oc][rr] = accT[oc][rr];
        #pragma unroll
        for (int oc = 0; oc < 4; ++oc)
            dpp_sum8_x4(S[oc][0], S[oc][1], S[oc][2], S[oc][3]);  // sum over ic
        #pragma unroll
        for (int oc = 0; oc < 4; ++oc) {
            #pragma unroll
            for (int rr = 0; rr < 4; ++rr)
                S[oc][rr] = fmaf(0.25f, S[oc][rr], biasT[oc][rr]);  // preact
            float t = S[oc][0]*S[oc][0];
            t = fmaf(S[oc][1], S[oc][1], t);
            t = fmaf(S[oc][2], S[oc][2], t);
            t = fmaf(S[oc][3], S[oc][3], t);
            sqv[oc] = t;
        }
        join16_x4(sqv[0], sqv[1], sqv[2], sqv[3]);   // sum over g (norm^2)
        join32_x4(sqv[0], sqv[1], sqv[2], sqv[3]);
        #pragma unroll
        for (int oc = 0; oc < 4; ++oc) {
            float fac = __builtin_amdgcn_sqrtf(sqv[oc]) * __builtin_amdgcn_rcpf(1.f + sqv[oc]);
            #pragma unroll
            for (int rr = 0; rr < 4; ++rr) actT[oc][rr] = S[oc][rr] * fac;
        }
        #pragma unroll
        for (int oc = 0; oc < 4; ++oc) {
            float t = accT[oc][0]*actT[oc][0];
            t = fmaf(accT[oc][1], actT[oc][1], t);
            t = fmaf(accT[oc][2], actT[oc][2], t);
            t = fmaf(accT[oc][3], actT[oc][3], t);
            logit[oc] = t;
        }
        join16_x4(logit[0], logit[1], logit[2], logit[3]);  // sum over g
        join32_x4(logit[0], logit[1], logit[2], logit[3]);

        // ---- iterations 2 and 3 ----
        #pragma unroll
        for (int it = 1; it < 3; ++it) {
            // per-lane softmax over oc (lane owns pi); no-max (|logit| small)
            float e0 = __expf(logit[0]), e1 = __expf(logit[1]);
            float e2 = __expf(logit[2]), e3 = __expf(logit[3]);
            float inv = __builtin_amdgcn_rcpf((e0 + e1) + (e2 + e3));
            float rt[4] = {e0*inv, e1*inv, e2*inv, e3*inv};
            #pragma unroll
            for (int oc = 0; oc < 4; ++oc)
                #pragma unroll
                for (int rr = 0; rr < 4; ++rr) S[oc][rr] = rt[oc]*accT[oc][rr];
            #pragma unroll
            for (int oc = 0; oc < 4; ++oc)
                dpp_sum8_x4(S[oc][0], S[oc][1], S[oc][2], S[oc][3]);
            #pragma unroll
            for (int oc = 0; oc < 4; ++oc) {
                #pragma unroll
                for (int rr = 0; rr < 4; ++rr) S[oc][rr] += biasT[oc][rr];
                float t = S[oc][0]*S[oc][0];
                t = fmaf(S[oc][1], S[oc][1], t);
                t = fmaf(S[oc][2], S[oc][2], t);
                t = fmaf(S[oc][3], S[oc][3], t);
                sqv[oc] = t;
            }
            join16_x4(sqv[0], sqv[1], sqv[2], sqv[3]);
            join32_x4(sqv[0], sqv[1], sqv[2], sqv[3]);
            #pragma unroll
            for (int oc = 0; oc < 4; ++oc) {
                float fac = __builtin_amdgcn_sqrtf(sqv[oc]) * __builtin_amdgcn_rcpf(1.f + sqv[oc]);
                #pragma unroll
                for (int rr = 0; rr < 4; ++rr) actT[oc][rr] = S[oc][rr] * fac;
            }
            if (it == 1) {
                float upd[4];
                #pragma unroll
                for (int oc = 0; oc < 4; ++oc) {
                    float t = accT[oc][0]*actT[oc][0];
                    t = fmaf(accT[oc][1], actT[oc][1], t);
                    t = fmaf(accT[oc][2], actT[oc][2], t);
                    t = fmaf(accT[oc][3], actT[oc][3], t);
                    upd[oc] = t;
                }
                join16_x4(upd[0], upd[1], upd[2], upd[3]);
                join32_x4(upd[0], upd[1], upd[2], upd[3]);
                #pragma unroll
                for (int oc = 0; oc < 4; ++oc) logit[oc] += upd[oc];
            }
        }

        // ---- store: lanes with ic==0 carry each (position, g) once ----
        if (icl == 0) {
            const int oy = 2*y + py;
            const int ox = 2*(x0 + p_) + px;
            float* op = out + ((((size_t)b*112 + oy)*112 + ox)*64 + g*4);
            #pragma unroll
            for (int oc = 0; oc < 4; ++oc) {
                float4 v = make_float4(actT[oc][0], actT[oc][1],
                                       actT[oc][2], actT[oc][3]);
                *(float4*)(op + oc*16) = v;
            }
        }

        x0 += 2;
        if (x0 >= 56) { x0 -= 56; ++y; }
    }
}

extern "C" void kernel_launch(void* const* d_in, const int* in_sizes, int n_in,
                              void* d_out, int out_size, void* d_ws, size_t ws_size,
                              hipStream_t stream) {
    const float* in  = (const float*)d_in[0];
    const float* Wt  = (const float*)d_in[1];
    const float* bia = (const float*)d_in[2];
    float* out = (float*)d_out;
    hipLaunchKernelGGL(caps_deconv_route, dim3(2560), dim3(256), 0, stream,
                       in, Wt, bia, out);
}

// Round 16
// 73.139 us; speedup vs baseline: 1.0307x; 1.0307x over previous
//
#include <hip/hip_runtime.h>
#include <hip/hip_bf16.h>

// DeconvCapsuleLayer fused kernel, round 16.
// = round 13 EXACTLY (best known: 64.8us, dual-layout acc+accT routing,
// buffer-OOB loads, cvt_pk, raw sqrt) with occupancy pushed 5 -> 8 waves/SIMD:
//   - __launch_bounds__(256,8): reg cap 64. R13 compiles to VGPR=40 (cvt_pk
//     and raw-sqrt shrank it from the ~88 that made R9's (256,8) spill), so
//     it now fits with headroom. LDS 19456B x 8 blocks = 155.6KB <= 160KB.
//   - grid 2048 = 8 blocks/CU x 256 CU: ENTIRE grid resident in ONE round,
//     zero dispatch tail. Per (b,cls): 256 waves = 32x7 + 224x6 = 1568 pairs.
// R15's pure-T routing REVERTED (it added ~20us of DPP work; the dual-layout
// + 4 LDS bridges is the VALU-minimal form per R4/R13/R15 triangulation).
//
// Conv-transpose (stride 2, K=4, SAME -> pad 1): with o = 2*y+py:
//   ky = 2*ty + (py^1), iy = y + py - ty, valid iff 0<=iy<56 (same for x).

typedef __attribute__((ext_vector_type(8))) short bf16x8;
typedef __attribute__((ext_vector_type(4))) float f32x4;

// 8 floats (two f32x4) -> bf16x8 via 4x native packed converts (RNE).
static __device__ __forceinline__ bf16x8 cvt8(f32x4 a, f32x4 b) {
    union { unsigned u[4]; bf16x8 v; } r;
    asm("v_cvt_pk_bf16_f32 %0, %1, %2" : "=v"(r.u[0]) : "v"(a[0]), "v"(a[1]));
    asm("v_cvt_pk_bf16_f32 %0, %1, %2" : "=v"(r.u[1]) : "v"(a[2]), "v"(a[3]));
    asm("v_cvt_pk_bf16_f32 %0, %1, %2" : "=v"(r.u[2]) : "v"(b[0]), "v"(b[1]));
    asm("v_cvt_pk_bf16_f32 %0, %1, %2" : "=v"(r.u[3]) : "v"(b[2]), "v"(b[3]));
    return r.v;
}

// Build a raw-buffer SRD (stride=0 -> num_records in BYTES, raw dword mode).
static __device__ __forceinline__ __amdgpu_buffer_rsrc_t
make_srd(const void* base, int nrec) {
    uintptr_t p = (uintptr_t)base;
    unsigned lo = (unsigned)__builtin_amdgcn_readfirstlane((int)p);
    unsigned hi = (unsigned)__builtin_amdgcn_readfirstlane((int)(p >> 32));
    nrec = __builtin_amdgcn_readfirstlane(nrec);
    void* bp = (void*)(((uintptr_t)hi << 32) | lo);
    return __builtin_amdgcn_make_buffer_rsrc(bp, (short)0, nrec, 0x00020000);
}

// Four interleaved 16-lane all-reduce sums (broadcast across each 16-lane row).
static __device__ __forceinline__ void dpp_sum16_x4(float& a, float& b,
                                                    float& c, float& d) {
    asm("s_nop 1\n\t"
        "v_add_f32_dpp %0, %0, %0 quad_perm:[1,0,3,2] row_mask:0xf bank_mask:0xf\n\t"
        "v_add_f32_dpp %1, %1, %1 quad_perm:[1,0,3,2] row_mask:0xf bank_mask:0xf\n\t"
        "v_add_f32_dpp %2, %2, %2 quad_perm:[1,0,3,2] row_mask:0xf bank_mask:0xf\n\t"
        "v_add_f32_dpp %3, %3, %3 quad_perm:[1,0,3,2] row_mask:0xf bank_mask:0xf\n\t"
        "v_add_f32_dpp %0, %0, %0 quad_perm:[2,3,0,1] row_mask:0xf bank_mask:0xf\n\t"
        "v_add_f32_dpp %1, %1, %1 quad_perm:[2,3,0,1] row_mask:0xf bank_mask:0xf\n\t"
        "v_add_f32_dpp %2, %2, %2 quad_perm:[2,3,0,1] row_mask:0xf bank_mask:0xf\n\t"
        "v_add_f32_dpp %3, %3, %3 quad_perm:[2,3,0,1] row_mask:0xf bank_mask:0xf\n\t"
        "v_add_f32_dpp %0, %0, %0 row_half_mirror row_mask:0xf bank_mask:0xf\n\t"
        "v_add_f32_dpp %1, %1, %1 row_half_mirror row_mask:0xf bank_mask:0xf\n\t"
        "v_add_f32_dpp %2, %2, %2 row_half_mirror row_mask:0xf bank_mask:0xf\n\t"
        "v_add_f32_dpp %3, %3, %3 row_half_mirror row_mask:0xf bank_mask:0xf\n\t"
        "v_add_f32_dpp %0, %0, %0 row_mirror row_mask:0xf bank_mask:0xf\n\t"
        "v_add_f32_dpp %1, %1, %1 row_mirror row_mask:0xf bank_mask:0xf\n\t"
        "v_add_f32_dpp %2, %2, %2 row_mirror row_mask:0xf bank_mask:0xf\n\t"
        "v_add_f32_dpp %3, %3, %3 row_mirror row_mask:0xf bank_mask:0xf"
        : "+v"(a), "+v"(b), "+v"(c), "+v"(d));
}

// xor16 pair-sum (v_permlane16_swap + add; both regs equal -> direction moot).
static __device__ __forceinline__ void join16_x4(float& p0, float& p1,
                                                 float& p2, float& p3) {
    float q0 = p0, q1 = p1, q2 = p2, q3 = p3;
    asm("s_nop 1\n\t"
        "v_permlane16_swap_b32 %0, %4\n\t"
        "v_permlane16_swap_b32 %1, %5\n\t"
        "v_permlane16_swap_b32 %2, %6\n\t"
        "v_permlane16_swap_b32 %3, %7"
        : "+v"(p0), "+v"(p1), "+v"(p2), "+v"(p3),
          "+v"(q0), "+v"(q1), "+v"(q2), "+v"(q3));
    p0 += q0; p1 += q1; p2 += q2; p3 += q3;
}

// xor32 pair-sum.
static __device__ __forceinline__ void join32_x4(float& p0, float& p1,
                                                 float& p2, float& p3) {
    float q0 = p0, q1 = p1, q2 = p2, q3 = p3;
    asm("s_nop 1\n\t"
        "v_permlane32_swap_b32 %0, %4\n\t"
        "v_permlane32_swap_b32 %1, %5\n\t"
        "v_permlane32_swap_b32 %2, %6\n\t"
        "v_permlane32_swap_b32 %3, %7"
        : "+v"(p0), "+v"(p1), "+v"(p2), "+v"(p3),
          "+v"(q0), "+v"(q1), "+v"(q2), "+v"(q3));
    p0 += q0; p1 += q1; p2 += q2; p3 += q3;
}

__global__ __launch_bounds__(256, 8)
void caps_deconv_route(const float* __restrict__ in, const float* __restrict__ Wt,
                       const float* __restrict__ bia, float* __restrict__ out) {
    const int tid  = threadIdx.x;
    const int lane = tid & 63;
    const int wid  = tid >> 6;

    // XCD-aware mapping: b = h&7 -> each XCD owns one batch. Grid 2048 =
    // 8 b x 4 cls x 64 blocks; per (b,cls): 256 waves = 32x7 + 224x6 pairs.
    const int h    = blockIdx.x;       // 0..2047
    const int b    = h & 7;
    const int r    = h >> 3;           // 0..255
    const int s64  = r >> 2;           // 0..63
    const int cls  = r & 3;
    const int py = cls >> 1, px = cls & 1;

    const int wv = s64*4 + wid;        // 0..255 within (b,cls)
    int start, np;
    if (wv < 32) { start = wv*7;      np = 7; }
    else         { start = wv*6 + 32; np = 6; }

    // ---- stage weights (this parity class) into LDS as bf16 B-fragments ----
    // uint4[(s*4 + ko)*64 + ch], ch = oc*16+oa; each uint4 = 8 bf16 (ci octet)
    __shared__ uint4 wlds[1024];        // 16 KB
    __shared__ float sw[4][192];        // per-wave bridge scratch (3 KB)
    for (int t = tid; t < 1024; t += 256) {
        const int s  = t >> 8;
        const int ko = (t >> 6) & 3;
        const int ch = t & 63;
        const int ky = 2*(s >> 1) + (py ^ 1);
        const int kx = 2*(s & 1)  + (px ^ 1);
        const float* wp = Wt + (((ky*4 + kx)*64 + ch)*32 + ko*8);
        const float4 w0 = *(const float4*)(wp);
        const float4 w1 = *(const float4*)(wp + 4);
        uint4 u;
        asm("v_cvt_pk_bf16_f32 %0, %1, %2" : "=v"(u.x) : "v"(w0.x), "v"(w0.y));
        asm("v_cvt_pk_bf16_f32 %0, %1, %2" : "=v"(u.y) : "v"(w0.z), "v"(w0.w));
        asm("v_cvt_pk_bf16_f32 %0, %1, %2" : "=v"(u.z) : "v"(w1.x), "v"(w1.y));
        asm("v_cvt_pk_bf16_f32 %0, %1, %2" : "=v"(u.w) : "v"(w1.z), "v"(w1.w));
        wlds[t] = u;
    }
    __syncthreads();

    const int col  = lane & 15;   // orig: oa | T: pi
    const int koct = lane >> 4;
    const int wbase = koct*64 + col;

    const int oa    = col;
    const int posl  = lane >> 5;        // orig C rows: position of the pair
    const int ich   = (lane >> 4) & 1;  // orig C rows: ic half
    const int a_pos = (lane >> 3) & 1;  // A rows: position
    const int a_ic  = lane & 7;         // A rows: ic
    const int pi    = col;              // T cols: pos*8+ic
    const int g     = koct;             // T rows: oa group (oa = g*4+r)
    const int posT  = pi >> 3;

    float bias_v[4];
    #pragma unroll
    for (int oc = 0; oc < 4; ++oc) bias_v[oc] = bia[oc*16 + oa];

    float* swa = sw[wid];        // act bridge: [pos][oc][oa] = 128 f32
    float* swr = sw[wid] + 128;  // route bridge: [pi][oc] = 64 f32

    // per-lane byte offset within one input row image (56 cols * 256 f32 * 4B)
    const int laneoff = a_pos*1024 + a_ic*128 + koct*32;

    int p0v = start * 2;
    int y  = p0v / 56;
    int x0 = p0v - y*56;   // pairs advance by 2; 56 even -> never crosses rows

    for (int i = 0; i < np; ++i) {
        // ---- per-row buffer descriptors (wave-uniform via readfirstlane) ----
        // ty=0 row iy = y+py; ty=1 row iy = y+py-1. Invalid row -> nrec=0.
        const int iy0 = y + py, iy1 = y + py - 1;
        const __amdgpu_buffer_rsrc_t srd0 = make_srd(
            (const char*)in + (size_t)(b*56 + (iy0 < 0 ? 0 : (iy0 > 55 ? 55 : iy0))) * 57344,
            ((unsigned)iy0 < 56u) ? 57344 : 0);
        const __amdgpu_buffer_rsrc_t srd1 = make_srd(
            (const char*)in + (size_t)(b*56 + (iy1 < 0 ? 0 : (iy1 > 55 ? 55 : iy1))) * 57344,
            ((unsigned)iy1 < 56u) ? 57344 : 0);
        // voffset: ix*1024 + laneoff; tx=1 -> -1024 (unsigned wrap -> OOB -> 0)
        const int voff0 = (x0 + px) * 1024 + laneoff;
        const int voff1 = voff0 - 1024;

        // ---- A-tap loads: HW bounds check zeroes all out-of-range taps ----
        f32x4 t0a = __builtin_bit_cast(f32x4, __builtin_amdgcn_raw_buffer_load_b128(srd0, voff0,      0, 0));
        f32x4 t0b = __builtin_bit_cast(f32x4, __builtin_amdgcn_raw_buffer_load_b128(srd0, voff0 + 16, 0, 0));
        f32x4 t1a = __builtin_bit_cast(f32x4, __builtin_amdgcn_raw_buffer_load_b128(srd0, voff1,      0, 0));
        f32x4 t1b = __builtin_bit_cast(f32x4, __builtin_amdgcn_raw_buffer_load_b128(srd0, voff1 + 16, 0, 0));
        f32x4 t2a = __builtin_bit_cast(f32x4, __builtin_amdgcn_raw_buffer_load_b128(srd1, voff0,      0, 0));
        f32x4 t2b = __builtin_bit_cast(f32x4, __builtin_amdgcn_raw_buffer_load_b128(srd1, voff0 + 16, 0, 0));
        f32x4 t3a = __builtin_bit_cast(f32x4, __builtin_amdgcn_raw_buffer_load_b128(srd1, voff1,      0, 0));
        f32x4 t3b = __builtin_bit_cast(f32x4, __builtin_amdgcn_raw_buffer_load_b128(srd1, voff1 + 16, 0, 0));

        // ---- packed f32->bf16 conversion (native, RNE) ----
        bf16x8 af0 = cvt8(t0a, t0b);
        bf16x8 af1 = cvt8(t1a, t1b);
        bf16x8 af2 = cvt8(t2a, t2b);
        bf16x8 af3 = cvt8(t3a, t3b);

        // ---- votes both ways (C=0 inline on first MFMA of each chain) ----
        f32x4 acc[4], accT[4];
        __builtin_amdgcn_s_setprio(1);
        #pragma unroll
        for (int nt = 0; nt < 4; ++nt) {
            bf16x8 wf = __builtin_bit_cast(bf16x8, wlds[wbase + nt*16]);
            acc[nt]  = __builtin_amdgcn_mfma_f32_16x16x32_bf16(
                af0, wf, (f32x4){0.f,0.f,0.f,0.f}, 0, 0, 0);
            accT[nt] = __builtin_amdgcn_mfma_f32_16x16x32_bf16(
                wf, af0, (f32x4){0.f,0.f,0.f,0.f}, 0, 0, 0);
        }
        #pragma unroll
        for (int nt = 0; nt < 4; ++nt) {
            bf16x8 wf = __builtin_bit_cast(bf16x8, wlds[wbase + 256 + nt*16]);
            acc[nt]  = __builtin_amdgcn_mfma_f32_16x16x32_bf16(af1, wf, acc[nt], 0, 0, 0);
            accT[nt] = __builtin_amdgcn_mfma_f32_16x16x32_bf16(wf, af1, accT[nt], 0, 0, 0);
        }
        #pragma unroll
        for (int nt = 0; nt < 4; ++nt) {
            bf16x8 wf = __builtin_bit_cast(bf16x8, wlds[wbase + 512 + nt*16]);
            acc[nt]  = __builtin_amdgcn_mfma_f32_16x16x32_bf16(af2, wf, acc[nt], 0, 0, 0);
            accT[nt] = __builtin_amdgcn_mfma_f32_16x16x32_bf16(wf, af2, accT[nt], 0, 0, 0);
        }
        #pragma unroll
        for (int nt = 0; nt < 4; ++nt) {
            bf16x8 wf = __builtin_bit_cast(bf16x8, wlds[wbase + 768 + nt*16]);
            acc[nt]  = __builtin_amdgcn_mfma_f32_16x16x32_bf16(af3, wf, acc[nt], 0, 0, 0);
            accT[nt] = __builtin_amdgcn_mfma_f32_16x16x32_bf16(wf, af3, accT[nt], 0, 0, 0);
        }
        __builtin_amdgcn_s_setprio(0);
        // orig: lane(posl,ich,oa): acc[oc][q]  = votes[ic=ich*4+q][oc][oa]
        // T:    lane(pi,g):        accT[oc][r] = votes[pi][oc][oa=g*4+r]

        // ---- iter 1 (logits=0 -> route=0.25 exactly) ----
        float p[4], sq[4], act[4];
        #pragma unroll
        for (int oc = 0; oc < 4; ++oc)
            p[oc] = (acc[oc][0] + acc[oc][1]) + (acc[oc][2] + acc[oc][3]);
        join16_x4(p[0], p[1], p[2], p[3]);          // join ic halves
        #pragma unroll
        for (int oc = 0; oc < 4; ++oc) {
            p[oc] = fmaf(0.25f, p[oc], bias_v[oc]);
            sq[oc] = p[oc] * p[oc];
        }
        dpp_sum16_x4(sq[0], sq[1], sq[2], sq[3]);   // norm^2 over oa
        #pragma unroll
        for (int oc = 0; oc < 4; ++oc)
            act[oc] = p[oc] * (__builtin_amdgcn_sqrtf(sq[oc]) * __builtin_amdgcn_rcpf(1.f + sq[oc]));

        // act -> T layout (explicit drain: compiler barrier + LDS completion)
        if (ich == 0) {
            #pragma unroll
            for (int oc = 0; oc < 4; ++oc) swa[posl*64 + oc*16 + oa] = act[oc];
        }
        asm volatile("s_waitcnt lgkmcnt(0)" ::: "memory");
        float logit[4];
        #pragma unroll
        for (int oc = 0; oc < 4; ++oc) {
            float4 at = *(const float4*)&swa[posT*64 + oc*16 + g*4];
            float t = accT[oc][0]*at.x;
            t = fmaf(accT[oc][1], at.y, t);
            t = fmaf(accT[oc][2], at.z, t);
            t = fmaf(accT[oc][3], at.w, t);
            logit[oc] = t;
        }
        join16_x4(logit[0], logit[1], logit[2], logit[3]);  // sum over g pairs
        join32_x4(logit[0], logit[1], logit[2], logit[3]);  // sum across halves

        // ---- iterations 2 and 3 ----
        #pragma unroll
        for (int it = 1; it < 3; ++it) {
            // per-lane softmax over oc (lane owns pi); no-max (|logit| small)
            float e0 = __expf(logit[0]), e1 = __expf(logit[1]);
            float e2 = __expf(logit[2]), e3 = __expf(logit[3]);
            float inv = __builtin_amdgcn_rcpf((e0 + e1) + (e2 + e3));
            if (lane < 16) {
                float4 rt = make_float4(e0*inv, e1*inv, e2*inv, e3*inv);
                *(float4*)&swr[pi*4] = rt;
            }
            asm volatile("s_waitcnt lgkmcnt(0)" ::: "memory");
            const int rb = (posl*8 + ich*4) * 4;
            float4 rq0 = *(const float4*)&swr[rb];
            float4 rq1 = *(const float4*)&swr[rb + 4];
            float4 rq2 = *(const float4*)&swr[rb + 8];
            float4 rq3 = *(const float4*)&swr[rb + 12];

            p[0] = fmaf(rq3.x, acc[0][3], fmaf(rq2.x, acc[0][2],
                   fmaf(rq1.x, acc[0][1], rq0.x*acc[0][0])));
            p[1] = fmaf(rq3.y, acc[1][3], fmaf(rq2.y, acc[1][2],
                   fmaf(rq1.y, acc[1][1], rq0.y*acc[1][0])));
            p[2] = fmaf(rq3.z, acc[2][3], fmaf(rq2.z, acc[2][2],
                   fmaf(rq1.z, acc[2][1], rq0.z*acc[2][0])));
            p[3] = fmaf(rq3.w, acc[3][3], fmaf(rq2.w, acc[3][2],
                   fmaf(rq1.w, acc[3][1], rq0.w*acc[3][0])));
            join16_x4(p[0], p[1], p[2], p[3]);
            #pragma unroll
            for (int oc = 0; oc < 4; ++oc) {
                p[oc] += bias_v[oc];
                sq[oc] = p[oc] * p[oc];
            }
            dpp_sum16_x4(sq[0], sq[1], sq[2], sq[3]);
            #pragma unroll
            for (int oc = 0; oc < 4; ++oc)
                act[oc] = p[oc] * (__builtin_amdgcn_sqrtf(sq[oc]) * __builtin_amdgcn_rcpf(1.f + sq[oc]));

            if (it == 1) {
                if (ich == 0) {
                    #pragma unroll
                    for (int oc = 0; oc < 4; ++oc) swa[posl*64 + oc*16 + oa] = act[oc];
                }
                asm volatile("s_waitcnt lgkmcnt(0)" ::: "memory");
                float upd[4];
                #pragma unroll
                for (int oc = 0; oc < 4; ++oc) {
                    float4 at = *(const float4*)&swa[posT*64 + oc*16 + g*4];
                    float t = accT[oc][0]*at.x;
                    t = fmaf(accT[oc][1], at.y, t);
                    t = fmaf(accT[oc][2], at.z, t);
                    t = fmaf(accT[oc][3], at.w, t);
                    upd[oc] = t;
                }
                join16_x4(upd[0], upd[1], upd[2], upd[3]);
                join32_x4(upd[0], upd[1], upd[2], upd[3]);
                #pragma unroll
                for (int oc = 0; oc < 4; ++oc) logit[oc] += upd[oc];
            }
        }

        // ---- store activation (ich==0 lanes carry each position once) ----
        if (ich == 0) {
            const int oy = 2*y + py;
            const int ox = 2*(x0 + posl) + px;
            float* op = out + ((((size_t)b*112 + oy)*112 + ox)*64 + oa);
            #pragma unroll
            for (int oc = 0; oc < 4; ++oc) op[oc*16] = act[oc];
        }

        x0 += 2;
        if (x0 >= 56) { x0 -= 56; ++y; }
    }
}

extern "C" void kernel_launch(void* const* d_in, const int* in_sizes, int n_in,
                              void* d_out, int out_size, void* d_ws, size_t ws_size,
                              hipStream_t stream) {
    const float* in  = (const float*)d_in[0];
    const float* Wt  = (const float*)d_in[1];
    const float* bia = (const float*)d_in[2];
    float* out = (float*)d_out;
    hipLaunchKernelGGL(caps_deconv_route, dim3(2048), dim3(256), 0, stream,
                       in, Wt, bia, out);
}

// Round 17
// 64.216 us; speedup vs baseline: 1.1740x; 1.1389x over previous
//
#include <hip/hip_runtime.h>
#include <hip/hip_bf16.h>

// DeconvCapsuleLayer fused kernel, round 17.
// = round 13 EXACTLY (best known: 64.8us) with occupancy 5 -> 6 waves/SIMD:
//   - __launch_bounds__(256,6): reg cap ~80 (granule). True demand ~72-76
//     (trace VGPR_Count under-reports: 32 MFMA accumulators count against
//     the unified file -> (256,8)'s cap 64 spilled in R9/R16).
//   - grid 1536 = 6 blocks/CU x 256 CU: whole grid resident in ONE round.
//     Per (b,cls): 192 waves = 32x9 + 160x8 = 1568 pairs exactly.
// Validity gate: FETCH ~13MB / WRITE ~25MB. Spill signature -> revert to R13.
//
// Conv-transpose (stride 2, K=4, SAME -> pad 1): with o = 2*y+py:
//   ky = 2*ty + (py^1), iy = y + py - ty, valid iff 0<=iy<56 (same for x).

typedef __attribute__((ext_vector_type(8))) short bf16x8;
typedef __attribute__((ext_vector_type(4))) float f32x4;

// 8 floats (two f32x4) -> bf16x8 via 4x native packed converts (RNE).
static __device__ __forceinline__ bf16x8 cvt8(f32x4 a, f32x4 b) {
    union { unsigned u[4]; bf16x8 v; } r;
    asm("v_cvt_pk_bf16_f32 %0, %1, %2" : "=v"(r.u[0]) : "v"(a[0]), "v"(a[1]));
    asm("v_cvt_pk_bf16_f32 %0, %1, %2" : "=v"(r.u[1]) : "v"(a[2]), "v"(a[3]));
    asm("v_cvt_pk_bf16_f32 %0, %1, %2" : "=v"(r.u[2]) : "v"(b[0]), "v"(b[1]));
    asm("v_cvt_pk_bf16_f32 %0, %1, %2" : "=v"(r.u[3]) : "v"(b[2]), "v"(b[3]));
    return r.v;
}

// Build a raw-buffer SRD (stride=0 -> num_records in BYTES, raw dword mode).
static __device__ __forceinline__ __amdgpu_buffer_rsrc_t
make_srd(const void* base, int nrec) {
    uintptr_t p = (uintptr_t)base;
    unsigned lo = (unsigned)__builtin_amdgcn_readfirstlane((int)p);
    unsigned hi = (unsigned)__builtin_amdgcn_readfirstlane((int)(p >> 32));
    nrec = __builtin_amdgcn_readfirstlane(nrec);
    void* bp = (void*)(((uintptr_t)hi << 32) | lo);
    return __builtin_amdgcn_make_buffer_rsrc(bp, (short)0, nrec, 0x00020000);
}

// Four interleaved 16-lane all-reduce sums (broadcast across each 16-lane row).
static __device__ __forceinline__ void dpp_sum16_x4(float& a, float& b,
                                                    float& c, float& d) {
    asm("s_nop 1\n\t"
        "v_add_f32_dpp %0, %0, %0 quad_perm:[1,0,3,2] row_mask:0xf bank_mask:0xf\n\t"
        "v_add_f32_dpp %1, %1, %1 quad_perm:[1,0,3,2] row_mask:0xf bank_mask:0xf\n\t"
        "v_add_f32_dpp %2, %2, %2 quad_perm:[1,0,3,2] row_mask:0xf bank_mask:0xf\n\t"
        "v_add_f32_dpp %3, %3, %3 quad_perm:[1,0,3,2] row_mask:0xf bank_mask:0xf\n\t"
        "v_add_f32_dpp %0, %0, %0 quad_perm:[2,3,0,1] row_mask:0xf bank_mask:0xf\n\t"
        "v_add_f32_dpp %1, %1, %1 quad_perm:[2,3,0,1] row_mask:0xf bank_mask:0xf\n\t"
        "v_add_f32_dpp %2, %2, %2 quad_perm:[2,3,0,1] row_mask:0xf bank_mask:0xf\n\t"
        "v_add_f32_dpp %3, %3, %3 quad_perm:[2,3,0,1] row_mask:0xf bank_mask:0xf\n\t"
        "v_add_f32_dpp %0, %0, %0 row_half_mirror row_mask:0xf bank_mask:0xf\n\t"
        "v_add_f32_dpp %1, %1, %1 row_half_mirror row_mask:0xf bank_mask:0xf\n\t"
        "v_add_f32_dpp %2, %2, %2 row_half_mirror row_mask:0xf bank_mask:0xf\n\t"
        "v_add_f32_dpp %3, %3, %3 row_half_mirror row_mask:0xf bank_mask:0xf\n\t"
        "v_add_f32_dpp %0, %0, %0 row_mirror row_mask:0xf bank_mask:0xf\n\t"
        "v_add_f32_dpp %1, %1, %1 row_mirror row_mask:0xf bank_mask:0xf\n\t"
        "v_add_f32_dpp %2, %2, %2 row_mirror row_mask:0xf bank_mask:0xf\n\t"
        "v_add_f32_dpp %3, %3, %3 row_mirror row_mask:0xf bank_mask:0xf"
        : "+v"(a), "+v"(b), "+v"(c), "+v"(d));
}

// xor16 pair-sum (v_permlane16_swap + add; both regs equal -> direction moot).
static __device__ __forceinline__ void join16_x4(float& p0, float& p1,
                                                 float& p2, float& p3) {
    float q0 = p0, q1 = p1, q2 = p2, q3 = p3;
    asm("s_nop 1\n\t"
        "v_permlane16_swap_b32 %0, %4\n\t"
        "v_permlane16_swap_b32 %1, %5\n\t"
        "v_permlane16_swap_b32 %2, %6\n\t"
        "v_permlane16_swap_b32 %3, %7"
        : "+v"(p0), "+v"(p1), "+v"(p2), "+v"(p3),
          "+v"(q0), "+v"(q1), "+v"(q2), "+v"(q3));
    p0 += q0; p1 += q1; p2 += q2; p3 += q3;
}

// xor32 pair-sum.
static __device__ __forceinline__ void join32_x4(float& p0, float& p1,
                                                 float& p2, float& p3) {
    float q0 = p0, q1 = p1, q2 = p2, q3 = p3;
    asm("s_nop 1\n\t"
        "v_permlane32_swap_b32 %0, %4\n\t"
        "v_permlane32_swap_b32 %1, %5\n\t"
        "v_permlane32_swap_b32 %2, %6\n\t"
        "v_permlane32_swap_b32 %3, %7"
        : "+v"(p0), "+v"(p1), "+v"(p2), "+v"(p3),
          "+v"(q0), "+v"(q1), "+v"(q2), "+v"(q3));
    p0 += q0; p1 += q1; p2 += q2; p3 += q3;
}

__global__ __launch_bounds__(256, 6)
void caps_deconv_route(const float* __restrict__ in, const float* __restrict__ Wt,
                       const float* __restrict__ bia, float* __restrict__ out) {
    const int tid  = threadIdx.x;
    const int lane = tid & 63;
    const int wid  = tid >> 6;

    // XCD-aware mapping: b = h&7 -> each XCD owns one batch. Grid 1536 =
    // 8 b x 4 cls x 48 blocks; per (b,cls): 192 waves = 32x9 + 160x8 pairs.
    const int h    = blockIdx.x;       // 0..1535
    const int b    = h & 7;
    const int r    = h >> 3;           // 0..191
    const int s48  = r >> 2;           // 0..47
    const int cls  = r & 3;
    const int py = cls >> 1, px = cls & 1;

    const int wv = s48*4 + wid;        // 0..191 within (b,cls)
    int start, np;
    if (wv < 32) { start = wv*9;      np = 9; }
    else         { start = wv*8 + 32; np = 8; }

    // ---- stage weights (this parity class) into LDS as bf16 B-fragments ----
    // uint4[(s*4 + ko)*64 + ch], ch = oc*16+oa; each uint4 = 8 bf16 (ci octet)
    __shared__ uint4 wlds[1024];        // 16 KB
    __shared__ float sw[4][192];        // per-wave bridge scratch (3 KB)
    for (int t = tid; t < 1024; t += 256) {
        const int s  = t >> 8;
        const int ko = (t >> 6) & 3;
        const int ch = t & 63;
        const int ky = 2*(s >> 1) + (py ^ 1);
        const int kx = 2*(s & 1)  + (px ^ 1);
        const float* wp = Wt + (((ky*4 + kx)*64 + ch)*32 + ko*8);
        const float4 w0 = *(const float4*)(wp);
        const float4 w1 = *(const float4*)(wp + 4);
        uint4 u;
        asm("v_cvt_pk_bf16_f32 %0, %1, %2" : "=v"(u.x) : "v"(w0.x), "v"(w0.y));
        asm("v_cvt_pk_bf16_f32 %0, %1, %2" : "=v"(u.y) : "v"(w0.z), "v"(w0.w));
        asm("v_cvt_pk_bf16_f32 %0, %1, %2" : "=v"(u.z) : "v"(w1.x), "v"(w1.y));
        asm("v_cvt_pk_bf16_f32 %0, %1, %2" : "=v"(u.w) : "v"(w1.z), "v"(w1.w));
        wlds[t] = u;
    }
    __syncthreads();

    const int col  = lane & 15;   // orig: oa | T: pi
    const int koct = lane >> 4;
    const int wbase = koct*64 + col;

    const int oa    = col;
    const int posl  = lane >> 5;        // orig C rows: position of the pair
    const int ich   = (lane >> 4) & 1;  // orig C rows: ic half
    const int a_pos = (lane >> 3) & 1;  // A rows: position
    const int a_ic  = lane & 7;         // A rows: ic
    const int pi    = col;              // T cols: pos*8+ic
    const int g     = koct;             // T rows: oa group (oa = g*4+r)
    const int posT  = pi >> 3;

    float bias_v[4];
    #pragma unroll
    for (int oc = 0; oc < 4; ++oc) bias_v[oc] = bia[oc*16 + oa];

    float* swa = sw[wid];        // act bridge: [pos][oc][oa] = 128 f32
    float* swr = sw[wid] + 128;  // route bridge: [pi][oc] = 64 f32

    // per-lane byte offset within one input row image (56 cols * 256 f32 * 4B)
    const int laneoff = a_pos*1024 + a_ic*128 + koct*32;

    int p0v = start * 2;
    int y  = p0v / 56;
    int x0 = p0v - y*56;   // pairs advance by 2; 56 even -> never crosses rows

    for (int i = 0; i < np; ++i) {
        // ---- per-row buffer descriptors (wave-uniform via readfirstlane) ----
        // ty=0 row iy = y+py; ty=1 row iy = y+py-1. Invalid row -> nrec=0.
        const int iy0 = y + py, iy1 = y + py - 1;
        const __amdgpu_buffer_rsrc_t srd0 = make_srd(
            (const char*)in + (size_t)(b*56 + (iy0 < 0 ? 0 : (iy0 > 55 ? 55 : iy0))) * 57344,
            ((unsigned)iy0 < 56u) ? 57344 : 0);
        const __amdgpu_buffer_rsrc_t srd1 = make_srd(
            (const char*)in + (size_t)(b*56 + (iy1 < 0 ? 0 : (iy1 > 55 ? 55 : iy1))) * 57344,
            ((unsigned)iy1 < 56u) ? 57344 : 0);
        // voffset: ix*1024 + laneoff; tx=1 -> -1024 (unsigned wrap -> OOB -> 0)
        const int voff0 = (x0 + px) * 1024 + laneoff;
        const int voff1 = voff0 - 1024;

        // ---- A-tap loads: HW bounds check zeroes all out-of-range taps ----
        f32x4 t0a = __builtin_bit_cast(f32x4, __builtin_amdgcn_raw_buffer_load_b128(srd0, voff0,      0, 0));
        f32x4 t0b = __builtin_bit_cast(f32x4, __builtin_amdgcn_raw_buffer_load_b128(srd0, voff0 + 16, 0, 0));
        f32x4 t1a = __builtin_bit_cast(f32x4, __builtin_amdgcn_raw_buffer_load_b128(srd0, voff1,      0, 0));
        f32x4 t1b = __builtin_bit_cast(f32x4, __builtin_amdgcn_raw_buffer_load_b128(srd0, voff1 + 16, 0, 0));
        f32x4 t2a = __builtin_bit_cast(f32x4, __builtin_amdgcn_raw_buffer_load_b128(srd1, voff0,      0, 0));
        f32x4 t2b = __builtin_bit_cast(f32x4, __builtin_amdgcn_raw_buffer_load_b128(srd1, voff0 + 16, 0, 0));
        f32x4 t3a = __builtin_bit_cast(f32x4, __builtin_amdgcn_raw_buffer_load_b128(srd1, voff1,      0, 0));
        f32x4 t3b = __builtin_bit_cast(f32x4, __builtin_amdgcn_raw_buffer_load_b128(srd1, voff1 + 16, 0, 0));

        // ---- packed f32->bf16 conversion (native, RNE) ----
        bf16x8 af0 = cvt8(t0a, t0b);
        bf16x8 af1 = cvt8(t1a, t1b);
        bf16x8 af2 = cvt8(t2a, t2b);
        bf16x8 af3 = cvt8(t3a, t3b);

        // ---- votes both ways (C=0 inline on first MFMA of each chain) ----
        f32x4 acc[4], accT[4];
        __builtin_amdgcn_s_setprio(1);
        #pragma unroll
        for (int nt = 0; nt < 4; ++nt) {
            bf16x8 wf = __builtin_bit_cast(bf16x8, wlds[wbase + nt*16]);
            acc[nt]  = __builtin_amdgcn_mfma_f32_16x16x32_bf16(
                af0, wf, (f32x4){0.f,0.f,0.f,0.f}, 0, 0, 0);
            accT[nt] = __builtin_amdgcn_mfma_f32_16x16x32_bf16(
                wf, af0, (f32x4){0.f,0.f,0.f,0.f}, 0, 0, 0);
        }
        #pragma unroll
        for (int nt = 0; nt < 4; ++nt) {
            bf16x8 wf = __builtin_bit_cast(bf16x8, wlds[wbase + 256 + nt*16]);
            acc[nt]  = __builtin_amdgcn_mfma_f32_16x16x32_bf16(af1, wf, acc[nt], 0, 0, 0);
            accT[nt] = __builtin_amdgcn_mfma_f32_16x16x32_bf16(wf, af1, accT[nt], 0, 0, 0);
        }
        #pragma unroll
        for (int nt = 0; nt < 4; ++nt) {
            bf16x8 wf = __builtin_bit_cast(bf16x8, wlds[wbase + 512 + nt*16]);
            acc[nt]  = __builtin_amdgcn_mfma_f32_16x16x32_bf16(af2, wf, acc[nt], 0, 0, 0);
            accT[nt] = __builtin_amdgcn_mfma_f32_16x16x32_bf16(wf, af2, accT[nt], 0, 0, 0);
        }
        #pragma unroll
        for (int nt = 0; nt < 4; ++nt) {
            bf16x8 wf = __builtin_bit_cast(bf16x8, wlds[wbase + 768 + nt*16]);
            acc[nt]  = __builtin_amdgcn_mfma_f32_16x16x32_bf16(af3, wf, acc[nt], 0, 0, 0);
            accT[nt] = __builtin_amdgcn_mfma_f32_16x16x32_bf16(wf, af3, accT[nt], 0, 0, 0);
        }
        __builtin_amdgcn_s_setprio(0);
        // orig: lane(posl,ich,oa): acc[oc][q]  = votes[ic=ich*4+q][oc][oa]
        // T:    lane(pi,g):        accT[oc][r] = votes[pi][oc][oa=g*4+r]

        // ---- iter 1 (logits=0 -> route=0.25 exactly) ----
        float p[4], sq[4], act[4];
        #pragma unroll
        for (int oc = 0; oc < 4; ++oc)
            p[oc] = (acc[oc][0] + acc[oc][1]) + (acc[oc][2] + acc[oc][3]);
        join16_x4(p[0], p[1], p[2], p[3]);          // join ic halves
        #pragma unroll
        for (int oc = 0; oc < 4; ++oc) {
            p[oc] = fmaf(0.25f, p[oc], bias_v[oc]);
            sq[oc] = p[oc] * p[oc];
        }
        dpp_sum16_x4(sq[0], sq[1], sq[2], sq[3]);   // norm^2 over oa
        #pragma unroll
        for (int oc = 0; oc < 4; ++oc)
            act[oc] = p[oc] * (__builtin_amdgcn_sqrtf(sq[oc]) * __builtin_amdgcn_rcpf(1.f + sq[oc]));

        // act -> T layout (explicit drain: compiler barrier + LDS completion)
        if (ich == 0) {
            #pragma unroll
            for (int oc = 0; oc < 4; ++oc) swa[posl*64 + oc*16 + oa] = act[oc];
        }
        asm volatile("s_waitcnt lgkmcnt(0)" ::: "memory");
        float logit[4];
        #pragma unroll
        for (int oc = 0; oc < 4; ++oc) {
            float4 at = *(const float4*)&swa[posT*64 + oc*16 + g*4];
            float t = accT[oc][0]*at.x;
            t = fmaf(accT[oc][1], at.y, t);
            t = fmaf(accT[oc][2], at.z, t);
            t = fmaf(accT[oc][3], at.w, t);
            logit[oc] = t;
        }
        join16_x4(logit[0], logit[1], logit[2], logit[3]);  // sum over g pairs
        join32_x4(logit[0], logit[1], logit[2], logit[3]);  // sum across halves

        // ---- iterations 2 and 3 ----
        #pragma unroll
        for (int it = 1; it < 3; ++it) {
            // per-lane softmax over oc (lane owns pi); no-max (|logit| small)
            float e0 = __expf(logit[0]), e1 = __expf(logit[1]);
            float e2 = __expf(logit[2]), e3 = __expf(logit[3]);
            float inv = __builtin_amdgcn_rcpf((e0 + e1) + (e2 + e3));
            if (lane < 16) {
                float4 rt = make_float4(e0*inv, e1*inv, e2*inv, e3*inv);
                *(float4*)&swr[pi*4] = rt;
            }
            asm volatile("s_waitcnt lgkmcnt(0)" ::: "memory");
            const int rb = (posl*8 + ich*4) * 4;
            float4 rq0 = *(const float4*)&swr[rb];
            float4 rq1 = *(const float4*)&swr[rb + 4];
            float4 rq2 = *(const float4*)&swr[rb + 8];
            float4 rq3 = *(const float4*)&swr[rb + 12];

            p[0] = fmaf(rq3.x, acc[0][3], fmaf(rq2.x, acc[0][2],
                   fmaf(rq1.x, acc[0][1], rq0.x*acc[0][0])));
            p[1] = fmaf(rq3.y, acc[1][3], fmaf(rq2.y, acc[1][2],
                   fmaf(rq1.y, acc[1][1], rq0.y*acc[1][0])));
            p[2] = fmaf(rq3.z, acc[2][3], fmaf(rq2.z, acc[2][2],
                   fmaf(rq1.z, acc[2][1], rq0.z*acc[2][0])));
            p[3] = fmaf(rq3.w, acc[3][3], fmaf(rq2.w, acc[3][2],
                   fmaf(rq1.w, acc[3][1], rq0.w*acc[3][0])));
            join16_x4(p[0], p[1], p[2], p[3]);
            #pragma unroll
            for (int oc = 0; oc < 4; ++oc) {
                p[oc] += bias_v[oc];
                sq[oc] = p[oc] * p[oc];
            }
            dpp_sum16_x4(sq[0], sq[1], sq[2], sq[3]);
            #pragma unroll
            for (int oc = 0; oc < 4; ++oc)
                act[oc] = p[oc] * (__builtin_amdgcn_sqrtf(sq[oc]) * __builtin_amdgcn_rcpf(1.f + sq[oc]));

            if (it == 1) {
                if (ich == 0) {
                    #pragma unroll
                    for (int oc = 0; oc < 4; ++oc) swa[posl*64 + oc*16 + oa] = act[oc];
                }
                asm volatile("s_waitcnt lgkmcnt(0)" ::: "memory");
                float upd[4];
                #pragma unroll
                for (int oc = 0; oc < 4; ++oc) {
                    float4 at = *(const float4*)&swa[posT*64 + oc*16 + g*4];
                    float t = accT[oc][0]*at.x;
                    t = fmaf(accT[oc][1], at.y, t);
                    t = fmaf(accT[oc][2], at.z, t);
                    t = fmaf(accT[oc][3], at.w, t);
                    upd[oc] = t;
                }
                join16_x4(upd[0], upd[1], upd[2], upd[3]);
                join32_x4(upd[0], upd[1], upd[2], upd[3]);
                #pragma unroll
                for (int oc = 0; oc < 4; ++oc) logit[oc] += upd[oc];
            }
        }

        // ---- store activation (ich==0 lanes carry each position once) ----
        if (ich == 0) {
            const int oy = 2*y + py;
            const int ox = 2*(x0 + posl) + px;
            float* op = out + ((((size_t)b*112 + oy)*112 + ox)*64 + oa);
            #pragma unroll
            for (int oc = 0; oc < 4; ++oc) op[oc*16] = act[oc];
        }

        x0 += 2;
        if (x0 >= 56) { x0 -= 56; ++y; }
    }
}

extern "C" void kernel_launch(void* const* d_in, const int* in_sizes, int n_in,
                              void* d_out, int out_size, void* d_ws, size_t ws_size,
                              hipStream_t stream) {
    const float* in  = (const float*)d_in[0];
    const float* Wt  = (const float*)d_in[1];
    const float* bia = (const float*)d_in[2];
    float* out = (float*)d_out;
    hipLaunchKernelGGL(caps_deconv_route, dim3(1536), dim3(256), 0, stream,
                       in, Wt, bia, out);
}